// Round 7
// baseline (194.518 us; speedup 1.0000x reference)
//
#include <hip/hip_runtime.h>
#include <hip/hip_bf16.h>

#define NN 512
#define NSTEPS 5
#define CSTR 32   // counter stride in ints: 128 B per counter line

typedef __attribute__((ext_vector_type(8))) short short8;
typedef __attribute__((ext_vector_type(4))) float floatx4;

static __device__ __forceinline__ unsigned short f2bf(float f) {
    union { float f; unsigned u; } x; x.f = f;
    unsigned r = x.u + 0x7fffu + ((x.u >> 16) & 1u);
    return (unsigned short)(r >> 16);
}

static __device__ __forceinline__ unsigned pk2bf(float a, float b) {
    __hip_bfloat162 h = __float22bfloat162_rn(make_float2(a, b));
    return *reinterpret_cast<unsigned*>(&h);
}

// ============================================================================
// Barrier-free fused kernel v5: 256 blocks x 512 threads, 2 nodes/block
// (v3 shape -- parallel per-node tails beat 2-blocks/CU, R6 measured).
// Sync via ONE epoch counter per step instead of 512 per-node flags:
//   producer: agent stores of its 64-float a-row, vmcnt(0), then ONE
//             fire-and-forget atomic_add(&cnt[s+1], 1)  (512 adds/step).
//   consumer: a SINGLE thread polls cnt[s] >= 512, then __syncthreads()
//             releases the block. Poll traffic: 256 loads/round vs ~1M for
//             per-node flags (R5/R6's hidden cost).
// Panels: 5 distinct write-once buffers -> no stale-line hazard for plain
// cached consumer loads (validated R4-R6). Plain launch (coop adds ~112us).
// ============================================================================
__global__ __launch_bounds__(512, 2) void fused5_kernel(
    const float* __restrict__ J, const float* __restrict__ b,
    const float* __restrict__ W1, const float* __restrict__ b1,
    const float* __restrict__ W2, const float* __restrict__ b2,
    const float* __restrict__ W3, const float* __restrict__ b3,
    const float* __restrict__ W_ih, const float* __restrict__ b_ih,
    const float* __restrict__ W_hh, const float* __restrict__ b_hh,
    const float* __restrict__ Wr1, const float* __restrict__ br1,
    const float* __restrict__ Wr2, const float* __restrict__ br2,
    const float* __restrict__ Wr3, const float* __restrict__ br3,
    float* __restrict__ aP, int* __restrict__ cnt,
    float* __restrict__ out)
{
    const int tid = threadIdx.x;
    const int bid = blockIdx.x;
    const int nd = tid >> 8;          // which of the block's 2 nodes
    const int tl = tid & 255;         // local tid within node group
    const int j  = bid * 2 + nd;
    const int l  = tid & 63, w4 = tl >> 6;
    const int m  = l & 15,  q  = l >> 4;

    __shared__ float smW1hi[64][16], smW1hj[64][16];
    __shared__ float smC[2][64], smAbias[2][64], smCbias[2][64];
    __shared__ float smWave[2][4][64], smMacc[2][64];
    __shared__ float smGin[2][48], smGi[2][48], smGh[2][48];
    __shared__ float smH[2][16], smY[2][64], smR[2][2];

    // Drop stale clean L1/L2 lines of the workspace (harness poison-fill).
    __builtin_amdgcn_fence(__ATOMIC_ACQUIRE, "agent");

    // ---- publish a^1 (bias-only, h0=0) + per-node meta ----
    if (tid < 128) {
        int nd0 = tid >> 6, o = tid & 63;
        int j0 = bid*2 + nd0;
        float bj0 = b[j0];
        const float* w1r = W1 + o*35;
        float ab = bj0 * w1r[33];
        smAbias[nd0][o] = ab;
        float cb = bj0 * w1r[34] + b1[o];
        smCbias[nd0][o] = cb;
        smC[nd0][o] = cb;                  // h0 = 0 -> c0 bias-only
        __hip_atomic_store(&aP[32768 + j0*64 + o], ab,
                           __ATOMIC_RELAXED, __HIP_MEMORY_SCOPE_AGENT);
    }
    if (tid < 128) {   // waves 0,1 whole: wave-uniform vmcnt, one add each
        asm volatile("s_waitcnt vmcnt(0)" ::: "memory");
        if ((tid & 63) == 0)
            __hip_atomic_fetch_add(&cnt[1*CSTR], 1,
                                   __ATOMIC_RELAXED, __HIP_MEMORY_SCOPE_AGENT);
    }
    if (tid >= 128 && tid < 160) {
        int nd0 = (tid - 128) >> 4, o = (tid - 128) & 15;
        smH[nd0][o] = 0.f;
    }
    if (tid < 64) {
        const float* w1r = W1 + tid*35;
        #pragma unroll
        for (int s0 = 0; s0 < 16; ++s0) {
            smW1hi[tid][s0] = w1r[s0];
            smW1hj[tid][s0] = w1r[16 + s0];
        }
    }

    // J column for this node (i = w4*128 + c8*16 + m), once
    float Jr[8];
    #pragma unroll
    for (int c8 = 0; c8 < 8; ++c8)
        Jr[c8] = J[(w4*128 + c8*16 + m)*512 + j];

    // wJ vectors for this lane's o-set
    floatx4 wva, wvb, wvc, wvd;
    #pragma unroll
    for (int e = 0; e < 4; ++e) {
        wva[e] = W1[(q*8 + e)*35 + 32];
        wvb[e] = W1[(q*8 + 4 + e)*35 + 32];
        wvc[e] = W1[(32 + q*8 + e)*35 + 32];
        wvd[e] = W1[(32 + q*8 + 4 + e)*35 + 32];
    }

    // W2 B-fragments, in-register, once. B[k][n] = W2[n][k]
    short8 bfw[4][2];
    #pragma unroll
    for (int nt = 0; nt < 4; ++nt) {
        #pragma unroll
        for (int ks = 0; ks < 2; ++ks) {
            union { short8 s; unsigned short us[8]; } tpk;
            int n = nt*16 + m;
            #pragma unroll
            for (int jj = 0; jj < 8; ++jj)
                tpk.us[jj] = f2bf(W2[n*64 + ks*32 + q*8 + jj]);
            bfw[nt][ks] = tpk.s;
        }
    }
    float b2n[4];
    #pragma unroll
    for (int nt = 0; nt < 4; ++nt) b2n[nt] = b2[nt*16 + m];

    __syncthreads();   // smC / smW1 / smH ready

    for (int t = 0; t < NSTEPS; ++t) {
        const int last = (t == NSTEPS - 1);
        const int s = t + 1;               // panel generation consumed now

        floatx4 cva, cvb, cvc, cvd;
        #pragma unroll
        for (int e = 0; e < 4; ++e) {
            cva[e] = smC[nd][q*8 + e];
            cvb[e] = smC[nd][q*8 + 4 + e];
            cvc[e] = smC[nd][32 + q*8 + e];
            cvd[e] = smC[nd][32 + q*8 + 4 + e];
        }

        // single-thread counter poll, then block-wide release
        if (tid == 0) {
            while (__hip_atomic_load(&cnt[s*CSTR], __ATOMIC_RELAXED,
                                     __HIP_MEMORY_SCOPE_AGENT) < NN)
                __builtin_amdgcn_s_sleep(2);
        }
        __syncthreads();

        floatx4 acc[4];
        #pragma unroll
        for (int nt = 0; nt < 4; ++nt) acc[nt] = (floatx4){0.f,0.f,0.f,0.f};

        const floatx4* a4 = (const floatx4*)(aP + (size_t)s*32768);

        for (int c8 = 0; c8 < 8; ++c8) {
            int i = w4*128 + c8*16 + m;
            float Jij = Jr[c8];
            floatx4 av0 = a4[i*16 + q*2],     av1 = a4[i*16 + q*2 + 1];
            floatx4 av2 = a4[i*16 + 8 + q*2], av3 = a4[i*16 + 8 + q*2 + 1];
            floatx4 x0, x1, x2, x3;
            #pragma unroll
            for (int e = 0; e < 4; ++e) {
                x0[e] = fmaxf(fmaf(Jij, wva[e], av0[e]) + cva[e], 0.f);
                x1[e] = fmaxf(fmaf(Jij, wvb[e], av1[e]) + cvb[e], 0.f);
                x2[e] = fmaxf(fmaf(Jij, wvc[e], av2[e]) + cvc[e], 0.f);
                x3[e] = fmaxf(fmaf(Jij, wvd[e], av3[e]) + cvd[e], 0.f);
            }
            union { short8 s; unsigned u[4]; } fa0, fa1;
            fa0.u[0] = pk2bf(x0[0], x0[1]); fa0.u[1] = pk2bf(x0[2], x0[3]);
            fa0.u[2] = pk2bf(x1[0], x1[1]); fa0.u[3] = pk2bf(x1[2], x1[3]);
            fa1.u[0] = pk2bf(x2[0], x2[1]); fa1.u[1] = pk2bf(x2[2], x2[3]);
            fa1.u[2] = pk2bf(x3[0], x3[1]); fa1.u[3] = pk2bf(x3[2], x3[3]);
            #pragma unroll
            for (int nt = 0; nt < 4; ++nt) {
                floatx4 d = {0.f,0.f,0.f,0.f};
                d = __builtin_amdgcn_mfma_f32_16x16x32_bf16(fa0.s, bfw[nt][0], d, 0, 0, 0);
                d = __builtin_amdgcn_mfma_f32_16x16x32_bf16(fa1.s, bfw[nt][1], d, 0, 0, 0);
                #pragma unroll
                for (int r = 0; r < 4; ++r)
                    acc[nt][r] += fmaxf(d[r] + b2n[nt], 0.f);
            }
        }

        // reduce rows within wave, stage h into smGin
        #pragma unroll
        for (int nt = 0; nt < 4; ++nt) {
            float v = acc[nt][0] + acc[nt][1] + acc[nt][2] + acc[nt][3];
            v += __shfl_xor(v, 16);
            v += __shfl_xor(v, 32);
            if (l < 16) smWave[nd][w4][nt*16 + l] = v;
        }
        if (tl < 16) smGin[nd][tl] = smH[nd][tl];
        __syncthreads();
        if (tl < 64) smMacc[nd][tl] = smWave[nd][0][tl] + smWave[nd][1][tl]
                                    + smWave[nd][2][tl] + smWave[nd][3][tl];
        __syncthreads();

        // msg = W3 @ macc + 512*b3
        {
            int o = tl >> 3, p = tl & 7;
            const floatx4* W3v = (const floatx4*)W3;
            floatx4 wv0 = W3v[o*16 + p*2], wv1 = W3v[o*16 + p*2 + 1];
            float part = 0.f;
            #pragma unroll
            for (int e = 0; e < 4; ++e) {
                part = fmaf(wv0[e], smMacc[nd][p*8 + e], part);
                part = fmaf(wv1[e], smMacc[nd][p*8 + 4 + e], part);
            }
            part += __shfl_xor(part, 1);
            part += __shfl_xor(part, 2);
            part += __shfl_xor(part, 4);
            if (p == 0) smGin[nd][16 + o] = part + 512.f * b3[o];
        }
        __syncthreads();

        // GRU gates
        if (tl < 192) {
            int o = tl >> 2, p = tl & 3;
            const floatx4* Wv = (const floatx4*)W_ih;
            floatx4 w0 = Wv[o*12 + p*3], w1 = Wv[o*12 + p*3 + 1], w2 = Wv[o*12 + p*3 + 2];
            int k0 = p*12;
            float part = 0.f;
            #pragma unroll
            for (int e = 0; e < 4; ++e) {
                part = fmaf(w0[e], smGin[nd][k0 + e], part);
                part = fmaf(w1[e], smGin[nd][k0 + 4 + e], part);
                part = fmaf(w2[e], smGin[nd][k0 + 8 + e], part);
            }
            part += __shfl_xor(part, 1);
            part += __shfl_xor(part, 2);
            if (p == 0) smGi[nd][o] = part + b_ih[o];
        } else if (tl < 240) {
            int o = tl - 192;
            const floatx4* Wv = (const floatx4*)W_hh;
            floatx4 w0 = Wv[o*4], w1 = Wv[o*4+1], w2 = Wv[o*4+2], w3 = Wv[o*4+3];
            float s2 = b_hh[o];
            #pragma unroll
            for (int e = 0; e < 4; ++e) {
                s2 = fmaf(w0[e], smGin[nd][e],      s2);
                s2 = fmaf(w1[e], smGin[nd][4 + e],  s2);
                s2 = fmaf(w2[e], smGin[nd][8 + e],  s2);
                s2 = fmaf(w3[e], smGin[nd][12 + e], s2);
            }
            smGh[nd][o] = s2;
        }
        __syncthreads();

        if (tl < 16) {
            float r = 1.f / (1.f + __expf(-(smGi[nd][tl] + smGh[nd][tl])));
            float z = 1.f / (1.f + __expf(-(smGi[nd][16+tl] + smGh[nd][16+tl])));
            float n = tanhf(smGi[nd][32+tl] + r * smGh[nd][32+tl]);
            float hn = (1.f - z)*n + z*smGin[nd][tl];
            smH[nd][tl] = hn;
        }
        __syncthreads();

        if (!last) {
            if (tl < 128) {
                int o = tl & 63, sel = tl >> 6;
                const floatx4* Wv = (const floatx4*)(sel ? &smW1hj[0][0] : &smW1hi[0][0]);
                floatx4 w0 = Wv[o*4], w1 = Wv[o*4+1], w2 = Wv[o*4+2], w3 = Wv[o*4+3];
                float sacc = 0.f;
                #pragma unroll
                for (int e = 0; e < 4; ++e) {
                    sacc = fmaf(w0[e], smH[nd][e],      sacc);
                    sacc = fmaf(w1[e], smH[nd][4 + e],  sacc);
                    sacc = fmaf(w2[e], smH[nd][8 + e],  sacc);
                    sacc = fmaf(w3[e], smH[nd][12 + e], sacc);
                }
                if (sel == 0) {
                    // publish next panel row straight to the coherent point
                    __hip_atomic_store(&aP[(size_t)(s+1)*32768 + j*64 + o],
                                       sacc + smAbias[nd][o],
                                       __ATOMIC_RELAXED, __HIP_MEMORY_SCOPE_AGENT);
                } else {
                    smC[nd][o] = sacc + smCbias[nd][o];
                }
            }
            if (tl < 64) {   // producer wave: per-wave vmcnt, one add
                asm volatile("s_waitcnt vmcnt(0)" ::: "memory");
                if (tl == 0)
                    __hip_atomic_fetch_add(&cnt[(s+1)*CSTR], 1,
                                           __ATOMIC_RELAXED, __HIP_MEMORY_SCOPE_AGENT);
            }
            __syncthreads();   // protects smC for next iteration's reads
        } else {
            if (tl < 64) {
                const floatx4* Wv = (const floatx4*)Wr1;
                floatx4 w0 = Wv[tl*4], w1 = Wv[tl*4+1], w2 = Wv[tl*4+2], w3 = Wv[tl*4+3];
                float sacc = br1[tl];
                #pragma unroll
                for (int e = 0; e < 4; ++e) {
                    sacc = fmaf(w0[e], smH[nd][e],      sacc);
                    sacc = fmaf(w1[e], smH[nd][4 + e],  sacc);
                    sacc = fmaf(w2[e], smH[nd][8 + e],  sacc);
                    sacc = fmaf(w3[e], smH[nd][12 + e], sacc);
                }
                smY[nd][tl] = fmaxf(sacc, 0.f);
            }
            __syncthreads();
            {   // y2: 64 outputs x 64 inputs, 4 threads per output
                int o = tl >> 2, p = tl & 3;
                const floatx4* Wv = (const floatx4*)Wr2;
                floatx4 w0 = Wv[o*16 + p*4],     w1 = Wv[o*16 + p*4 + 1];
                floatx4 w2 = Wv[o*16 + p*4 + 2], w3 = Wv[o*16 + p*4 + 3];
                int k0 = p*16;
                float part = 0.f;
                #pragma unroll
                for (int e = 0; e < 4; ++e) {
                    part = fmaf(w0[e], smY[nd][k0 + e],      part);
                    part = fmaf(w1[e], smY[nd][k0 + 4 + e],  part);
                    part = fmaf(w2[e], smY[nd][k0 + 8 + e],  part);
                    part = fmaf(w3[e], smY[nd][k0 + 12 + e], part);
                }
                part += __shfl_xor(part, 1);
                part += __shfl_xor(part, 2);
                __syncthreads();
                if (p == 0) smY[nd][o] = fmaxf(part + br2[o], 0.f);
            }
            __syncthreads();
            if (tl < 128) {
                int ot = tl >> 6, p = tl & 63;
                float part = Wr3[ot*64 + p] * smY[nd][p];
                part += __shfl_xor(part, 1);
                part += __shfl_xor(part, 2);
                part += __shfl_xor(part, 4);
                part += __shfl_xor(part, 8);
                part += __shfl_xor(part, 16);
                part += __shfl_xor(part, 32);
                if (p == 0) smR[nd][ot] = part + br3[ot];
            }
            __syncthreads();
            if (tl == 0) {
                float e0 = 1.f/(1.f + __expf(-smR[nd][0]));
                float e1 = 1.f/(1.f + __expf(-smR[nd][1]));
                float tsum = e0 + e1;
                out[j*2]     = e0/tsum;
                out[j*2 + 1] = e1/tsum;
            }
        }
    }
}

extern "C" void kernel_launch(void* const* d_in, const int* in_sizes, int n_in,
                              void* d_out, int out_size, void* d_ws, size_t ws_size,
                              hipStream_t stream)
{
    const float* J    = (const float*)d_in[0];
    const float* b    = (const float*)d_in[1];
    const float* W1   = (const float*)d_in[2];
    const float* b1   = (const float*)d_in[3];
    const float* W2   = (const float*)d_in[4];
    const float* b2   = (const float*)d_in[5];
    const float* W3   = (const float*)d_in[6];
    const float* b3   = (const float*)d_in[7];
    const float* W_ih = (const float*)d_in[8];
    const float* b_ih = (const float*)d_in[9];
    const float* W_hh = (const float*)d_in[10];
    const float* b_hh = (const float*)d_in[11];
    const float* Wr1  = (const float*)d_in[12];
    const float* br1  = (const float*)d_in[13];
    const float* Wr2  = (const float*)d_in[14];
    const float* br2  = (const float*)d_in[15];
    const float* Wr3  = (const float*)d_in[16];
    const float* br3  = (const float*)d_in[17];
    float* outp = (float*)d_out;

    float* ws = (float*)d_ws;
    float* aP  = ws;                       // 6 * 32768 floats (slot 0 unused)
    int*   cnt = (int*)(ws + 6*32768);     // 8 counters * CSTR ints = 1 KB
    const size_t CNT_BYTES = 8u * CSTR * sizeof(int);

    // zero step counters; stream-ordered, graph-safe
    hipMemsetAsync((void*)cnt, 0, CNT_BYTES, stream);

    // PLAIN launch: 256 blocks x 512 threads, 1 block/CU, all co-resident.
    hipLaunchKernelGGL(fused5_kernel, dim3(NN/2), dim3(512), 0, stream,
        J, b, W1, b1, W2, b2, W3, b3, W_ih, b_ih, W_hh, b_hh,
        Wr1, br1, Wr2, br2, Wr3, br3, aP, cnt, outp);
}

// Round 8
// 178.039 us; speedup vs baseline: 1.0926x; 1.0926x over previous
//
#include <hip/hip_runtime.h>
#include <hip/hip_bf16.h>

#define NN 512
#define NSTEPS 5
#define CSTR 32   // counter stride in ints: 128 B per counter -> own L2/L3 line

typedef __attribute__((ext_vector_type(8))) short short8;
typedef __attribute__((ext_vector_type(4))) float floatx4;

static __device__ __forceinline__ unsigned short f2bf(float f) {
    union { float f; unsigned u; } x; x.f = f;
    unsigned r = x.u + 0x7fffu + ((x.u >> 16) & 1u);
    return (unsigned short)(r >> 16);
}

static __device__ __forceinline__ unsigned pk2bf(float a, float b) {
    __hip_bfloat162 h = __float22bfloat162_rn(make_float2(a, b));
    return *reinterpret_cast<unsigned*>(&h);
}

// ============================================================================
// v6: v3's verified fine-grained dataflow (256 blocks x 512 threads, 2 nodes/
// block, 90.6us) with GROUP-COUNTER readiness instead of per-node flags:
//   - 16 groups of 32 nodes; counter per (step,group), own 128B line.
//   - producer: agent stores of its 64-float a-row, vmcnt(0), ONE
//     fire-and-forget atomic_add(cnt[s][j>>5]).
//   - consumer wave w: its 128 rows = 4 groups; for each group: poll the
//     group counter to 32 with a UNIFORM-address load (1 merged request/wave
//     /round, ~500x less poll traffic than v3's per-lane 8-flag storm),
//     then immediately MFMA that group's 2 row-chunks -> compute on ready
//     groups overlaps stragglers (v3's partial-order win, which v5's single
//     all-512 counter destroyed: 114.8us vs 90.6).
// Panels: 5 distinct write-once buffers (no stale-line hazard, validated
// R4-R7). Plain launch (coop +112us). Counter-vs-flag semantics: counter==32
// implies all 32 producers drained their row stores (vmcnt before add).
// ============================================================================
__global__ __launch_bounds__(512, 2) void fused6_kernel(
    const float* __restrict__ J, const float* __restrict__ b,
    const float* __restrict__ W1, const float* __restrict__ b1,
    const float* __restrict__ W2, const float* __restrict__ b2,
    const float* __restrict__ W3, const float* __restrict__ b3,
    const float* __restrict__ W_ih, const float* __restrict__ b_ih,
    const float* __restrict__ W_hh, const float* __restrict__ b_hh,
    const float* __restrict__ Wr1, const float* __restrict__ br1,
    const float* __restrict__ Wr2, const float* __restrict__ br2,
    const float* __restrict__ Wr3, const float* __restrict__ br3,
    float* __restrict__ aP, int* __restrict__ cnt,
    float* __restrict__ out)
{
    const int tid = threadIdx.x;
    const int bid = blockIdx.x;
    const int nd = tid >> 8;          // which of the block's 2 nodes
    const int tl = tid & 255;         // local tid within node group
    const int j  = bid * 2 + nd;
    const int l  = tid & 63, w4 = tl >> 6;
    const int m  = l & 15,  q  = l >> 4;

    __shared__ float smW1hi[64][16], smW1hj[64][16];
    __shared__ float smC[2][64], smAbias[2][64], smCbias[2][64];
    __shared__ float smWave[2][4][64], smMacc[2][64];
    __shared__ float smGin[2][48], smGi[2][48], smGh[2][48];
    __shared__ float smH[2][16], smY[2][64], smR[2][2];

    // Drop stale clean L1/L2 lines of the workspace (harness poison-fill).
    __builtin_amdgcn_fence(__ATOMIC_ACQUIRE, "agent");

    // ---- publish a^1 (bias-only, h0=0) + per-node meta ----
    if (tid < 128) {
        int nd0 = tid >> 6, o = tid & 63;
        int j0 = bid*2 + nd0;
        float bj0 = b[j0];
        const float* w1r = W1 + o*35;
        float ab = bj0 * w1r[33];
        smAbias[nd0][o] = ab;
        float cb = bj0 * w1r[34] + b1[o];
        smCbias[nd0][o] = cb;
        smC[nd0][o] = cb;                  // h0 = 0 -> c0 bias-only
        __hip_atomic_store(&aP[32768 + j0*64 + o], ab,
                           __ATOMIC_RELAXED, __HIP_MEMORY_SCOPE_AGENT);
    }
    if (tid < 128) {   // waves 0,1 whole: wave-uniform vmcnt, one add each
        asm volatile("s_waitcnt vmcnt(0)" ::: "memory");
        if ((tid & 63) == 0) {
            int j0 = bid*2 + (tid >> 6);
            __hip_atomic_fetch_add(&cnt[(1*16 + (j0 >> 5))*CSTR], 1,
                                   __ATOMIC_RELAXED, __HIP_MEMORY_SCOPE_AGENT);
        }
    }
    if (tid >= 128 && tid < 160) {
        int nd0 = (tid - 128) >> 4, o = (tid - 128) & 15;
        smH[nd0][o] = 0.f;
    }
    if (tid < 64) {
        const float* w1r = W1 + tid*35;
        #pragma unroll
        for (int s0 = 0; s0 < 16; ++s0) {
            smW1hi[tid][s0] = w1r[s0];
            smW1hj[tid][s0] = w1r[16 + s0];
        }
    }

    // J column for this node (i = w4*128 + c8*16 + m), once
    float Jr[8];
    #pragma unroll
    for (int c8 = 0; c8 < 8; ++c8)
        Jr[c8] = J[(w4*128 + c8*16 + m)*512 + j];

    // wJ vectors for this lane's o-set
    floatx4 wva, wvb, wvc, wvd;
    #pragma unroll
    for (int e = 0; e < 4; ++e) {
        wva[e] = W1[(q*8 + e)*35 + 32];
        wvb[e] = W1[(q*8 + 4 + e)*35 + 32];
        wvc[e] = W1[(32 + q*8 + e)*35 + 32];
        wvd[e] = W1[(32 + q*8 + 4 + e)*35 + 32];
    }

    // W2 B-fragments, in-register, once. B[k][n] = W2[n][k]
    short8 bfw[4][2];
    #pragma unroll
    for (int nt = 0; nt < 4; ++nt) {
        #pragma unroll
        for (int ks = 0; ks < 2; ++ks) {
            union { short8 s; unsigned short us[8]; } tpk;
            int n = nt*16 + m;
            #pragma unroll
            for (int jj = 0; jj < 8; ++jj)
                tpk.us[jj] = f2bf(W2[n*64 + ks*32 + q*8 + jj]);
            bfw[nt][ks] = tpk.s;
        }
    }
    float b2n[4];
    #pragma unroll
    for (int nt = 0; nt < 4; ++nt) b2n[nt] = b2[nt*16 + m];

    __syncthreads();   // smC / smW1 / smH ready

    for (int t = 0; t < NSTEPS; ++t) {
        const int last = (t == NSTEPS - 1);
        const int s = t + 1;               // panel generation consumed now

        floatx4 cva, cvb, cvc, cvd;
        #pragma unroll
        for (int e = 0; e < 4; ++e) {
            cva[e] = smC[nd][q*8 + e];
            cvb[e] = smC[nd][q*8 + 4 + e];
            cvc[e] = smC[nd][32 + q*8 + e];
            cvd[e] = smC[nd][32 + q*8 + 4 + e];
        }

        floatx4 acc[4];
        #pragma unroll
        for (int nt = 0; nt < 4; ++nt) acc[nt] = (floatx4){0.f,0.f,0.f,0.f};

        const floatx4* a4 = (const floatx4*)(aP + (size_t)s*32768);

        // group-by-group: poll readiness of 32 rows, then MFMA their 2 chunks
        #pragma unroll
        for (int sub = 0; sub < 4; ++sub) {
            const int g = w4*4 + sub;
            // uniform-address poll: one merged request per wave per round
            while (__hip_atomic_load(&cnt[(s*16 + g)*CSTR], __ATOMIC_RELAXED,
                                     __HIP_MEMORY_SCOPE_AGENT) < 32)
                __builtin_amdgcn_s_sleep(1);
            asm volatile("" ::: "memory");   // no hoisting loads above poll

            #pragma unroll
            for (int cc = 0; cc < 2; ++cc) {
                const int c8 = sub*2 + cc;
                int i = w4*128 + c8*16 + m;
                float Jij = Jr[c8];
                floatx4 av0 = a4[i*16 + q*2],     av1 = a4[i*16 + q*2 + 1];
                floatx4 av2 = a4[i*16 + 8 + q*2], av3 = a4[i*16 + 8 + q*2 + 1];
                floatx4 x0, x1, x2, x3;
                #pragma unroll
                for (int e = 0; e < 4; ++e) {
                    x0[e] = fmaxf(fmaf(Jij, wva[e], av0[e]) + cva[e], 0.f);
                    x1[e] = fmaxf(fmaf(Jij, wvb[e], av1[e]) + cvb[e], 0.f);
                    x2[e] = fmaxf(fmaf(Jij, wvc[e], av2[e]) + cvc[e], 0.f);
                    x3[e] = fmaxf(fmaf(Jij, wvd[e], av3[e]) + cvd[e], 0.f);
                }
                union { short8 s; unsigned u[4]; } fa0, fa1;
                fa0.u[0] = pk2bf(x0[0], x0[1]); fa0.u[1] = pk2bf(x0[2], x0[3]);
                fa0.u[2] = pk2bf(x1[0], x1[1]); fa0.u[3] = pk2bf(x1[2], x1[3]);
                fa1.u[0] = pk2bf(x2[0], x2[1]); fa1.u[1] = pk2bf(x2[2], x2[3]);
                fa1.u[2] = pk2bf(x3[0], x3[1]); fa1.u[3] = pk2bf(x3[2], x3[3]);
                #pragma unroll
                for (int nt = 0; nt < 4; ++nt) {
                    floatx4 d = {0.f,0.f,0.f,0.f};
                    d = __builtin_amdgcn_mfma_f32_16x16x32_bf16(fa0.s, bfw[nt][0], d, 0, 0, 0);
                    d = __builtin_amdgcn_mfma_f32_16x16x32_bf16(fa1.s, bfw[nt][1], d, 0, 0, 0);
                    #pragma unroll
                    for (int r = 0; r < 4; ++r)
                        acc[nt][r] += fmaxf(d[r] + b2n[nt], 0.f);
                }
            }
        }

        // reduce rows within wave, stage h into smGin
        #pragma unroll
        for (int nt = 0; nt < 4; ++nt) {
            float v = acc[nt][0] + acc[nt][1] + acc[nt][2] + acc[nt][3];
            v += __shfl_xor(v, 16);
            v += __shfl_xor(v, 32);
            if (l < 16) smWave[nd][w4][nt*16 + l] = v;
        }
        if (tl < 16) smGin[nd][tl] = smH[nd][tl];
        __syncthreads();
        if (tl < 64) smMacc[nd][tl] = smWave[nd][0][tl] + smWave[nd][1][tl]
                                    + smWave[nd][2][tl] + smWave[nd][3][tl];
        __syncthreads();

        // msg = W3 @ macc + 512*b3
        {
            int o = tl >> 3, p = tl & 7;
            const floatx4* W3v = (const floatx4*)W3;
            floatx4 wv0 = W3v[o*16 + p*2], wv1 = W3v[o*16 + p*2 + 1];
            float part = 0.f;
            #pragma unroll
            for (int e = 0; e < 4; ++e) {
                part = fmaf(wv0[e], smMacc[nd][p*8 + e], part);
                part = fmaf(wv1[e], smMacc[nd][p*8 + 4 + e], part);
            }
            part += __shfl_xor(part, 1);
            part += __shfl_xor(part, 2);
            part += __shfl_xor(part, 4);
            if (p == 0) smGin[nd][16 + o] = part + 512.f * b3[o];
        }
        __syncthreads();

        // GRU gates
        if (tl < 192) {
            int o = tl >> 2, p = tl & 3;
            const floatx4* Wv = (const floatx4*)W_ih;
            floatx4 w0 = Wv[o*12 + p*3], w1 = Wv[o*12 + p*3 + 1], w2 = Wv[o*12 + p*3 + 2];
            int k0 = p*12;
            float part = 0.f;
            #pragma unroll
            for (int e = 0; e < 4; ++e) {
                part = fmaf(w0[e], smGin[nd][k0 + e], part);
                part = fmaf(w1[e], smGin[nd][k0 + 4 + e], part);
                part = fmaf(w2[e], smGin[nd][k0 + 8 + e], part);
            }
            part += __shfl_xor(part, 1);
            part += __shfl_xor(part, 2);
            if (p == 0) smGi[nd][o] = part + b_ih[o];
        } else if (tl < 240) {
            int o = tl - 192;
            const floatx4* Wv = (const floatx4*)W_hh;
            floatx4 w0 = Wv[o*4], w1 = Wv[o*4+1], w2 = Wv[o*4+2], w3 = Wv[o*4+3];
            float s2 = b_hh[o];
            #pragma unroll
            for (int e = 0; e < 4; ++e) {
                s2 = fmaf(w0[e], smGin[nd][e],      s2);
                s2 = fmaf(w1[e], smGin[nd][4 + e],  s2);
                s2 = fmaf(w2[e], smGin[nd][8 + e],  s2);
                s2 = fmaf(w3[e], smGin[nd][12 + e], s2);
            }
            smGh[nd][o] = s2;
        }
        __syncthreads();

        if (tl < 16) {
            float r = 1.f / (1.f + __expf(-(smGi[nd][tl] + smGh[nd][tl])));
            float z = 1.f / (1.f + __expf(-(smGi[nd][16+tl] + smGh[nd][16+tl])));
            float n = tanhf(smGi[nd][32+tl] + r * smGh[nd][32+tl]);
            float hn = (1.f - z)*n + z*smGin[nd][tl];
            smH[nd][tl] = hn;
        }
        __syncthreads();

        if (!last) {
            if (tl < 128) {
                int o = tl & 63, sel = tl >> 6;
                const floatx4* Wv = (const floatx4*)(sel ? &smW1hj[0][0] : &smW1hi[0][0]);
                floatx4 w0 = Wv[o*4], w1 = Wv[o*4+1], w2 = Wv[o*4+2], w3 = Wv[o*4+3];
                float sacc = 0.f;
                #pragma unroll
                for (int e = 0; e < 4; ++e) {
                    sacc = fmaf(w0[e], smH[nd][e],      sacc);
                    sacc = fmaf(w1[e], smH[nd][4 + e],  sacc);
                    sacc = fmaf(w2[e], smH[nd][8 + e],  sacc);
                    sacc = fmaf(w3[e], smH[nd][12 + e], sacc);
                }
                if (sel == 0) {
                    // publish next panel row straight to the coherent point
                    __hip_atomic_store(&aP[(size_t)(s+1)*32768 + j*64 + o],
                                       sacc + smAbias[nd][o],
                                       __ATOMIC_RELAXED, __HIP_MEMORY_SCOPE_AGENT);
                } else {
                    smC[nd][o] = sacc + smCbias[nd][o];
                }
            }
            if (tl < 64) {   // producer wave: per-wave vmcnt, one group add
                asm volatile("s_waitcnt vmcnt(0)" ::: "memory");
                if (tl == 0)
                    __hip_atomic_fetch_add(&cnt[((s+1)*16 + (j >> 5))*CSTR], 1,
                                           __ATOMIC_RELAXED, __HIP_MEMORY_SCOPE_AGENT);
            }
            __syncthreads();   // protects smC for next iteration's reads
        } else {
            if (tl < 64) {
                const floatx4* Wv = (const floatx4*)Wr1;
                floatx4 w0 = Wv[tl*4], w1 = Wv[tl*4+1], w2 = Wv[tl*4+2], w3 = Wv[tl*4+3];
                float sacc = br1[tl];
                #pragma unroll
                for (int e = 0; e < 4; ++e) {
                    sacc = fmaf(w0[e], smH[nd][e],      sacc);
                    sacc = fmaf(w1[e], smH[nd][4 + e],  sacc);
                    sacc = fmaf(w2[e], smH[nd][8 + e],  sacc);
                    sacc = fmaf(w3[e], smH[nd][12 + e], sacc);
                }
                smY[nd][tl] = fmaxf(sacc, 0.f);
            }
            __syncthreads();
            {   // y2: 64 outputs x 64 inputs, 4 threads per output
                int o = tl >> 2, p = tl & 3;
                const floatx4* Wv = (const floatx4*)Wr2;
                floatx4 w0 = Wv[o*16 + p*4],     w1 = Wv[o*16 + p*4 + 1];
                floatx4 w2 = Wv[o*16 + p*4 + 2], w3 = Wv[o*16 + p*4 + 3];
                int k0 = p*16;
                float part = 0.f;
                #pragma unroll
                for (int e = 0; e < 4; ++e) {
                    part = fmaf(w0[e], smY[nd][k0 + e],      part);
                    part = fmaf(w1[e], smY[nd][k0 + 4 + e],  part);
                    part = fmaf(w2[e], smY[nd][k0 + 8 + e],  part);
                    part = fmaf(w3[e], smY[nd][k0 + 12 + e], part);
                }
                part += __shfl_xor(part, 1);
                part += __shfl_xor(part, 2);
                __syncthreads();
                if (p == 0) smY[nd][o] = fmaxf(part + br2[o], 0.f);
            }
            __syncthreads();
            if (tl < 128) {
                int ot = tl >> 6, p = tl & 63;
                float part = Wr3[ot*64 + p] * smY[nd][p];
                part += __shfl_xor(part, 1);
                part += __shfl_xor(part, 2);
                part += __shfl_xor(part, 4);
                part += __shfl_xor(part, 8);
                part += __shfl_xor(part, 16);
                part += __shfl_xor(part, 32);
                if (p == 0) smR[nd][ot] = part + br3[ot];
            }
            __syncthreads();
            if (tl == 0) {
                float e0 = 1.f/(1.f + __expf(-smR[nd][0]));
                float e1 = 1.f/(1.f + __expf(-smR[nd][1]));
                float tsum = e0 + e1;
                out[j*2]     = e0/tsum;
                out[j*2 + 1] = e1/tsum;
            }
        }
    }
}

extern "C" void kernel_launch(void* const* d_in, const int* in_sizes, int n_in,
                              void* d_out, int out_size, void* d_ws, size_t ws_size,
                              hipStream_t stream)
{
    const float* J    = (const float*)d_in[0];
    const float* b    = (const float*)d_in[1];
    const float* W1   = (const float*)d_in[2];
    const float* b1   = (const float*)d_in[3];
    const float* W2   = (const float*)d_in[4];
    const float* b2   = (const float*)d_in[5];
    const float* W3   = (const float*)d_in[6];
    const float* b3   = (const float*)d_in[7];
    const float* W_ih = (const float*)d_in[8];
    const float* b_ih = (const float*)d_in[9];
    const float* W_hh = (const float*)d_in[10];
    const float* b_hh = (const float*)d_in[11];
    const float* Wr1  = (const float*)d_in[12];
    const float* br1  = (const float*)d_in[13];
    const float* Wr2  = (const float*)d_in[14];
    const float* br2  = (const float*)d_in[15];
    const float* Wr3  = (const float*)d_in[16];
    const float* br3  = (const float*)d_in[17];
    float* outp = (float*)d_out;

    float* ws = (float*)d_ws;
    float* aP  = ws;                       // 6 * 32768 floats (slot 0 unused)
    int*   cnt = (int*)(ws + 6*32768);     // (6 steps * 16 groups) * CSTR ints
    const size_t CNT_BYTES = 6u * 16u * CSTR * sizeof(int);   // 12 KB

    // zero group counters; stream-ordered, graph-safe
    hipMemsetAsync((void*)cnt, 0, CNT_BYTES, stream);

    // PLAIN launch: 256 blocks x 512 threads, 1 block/CU, all co-resident.
    hipLaunchKernelGGL(fused6_kernel, dim3(NN/2), dim3(512), 0, stream,
        J, b, W1, b1, W2, b2, W3, b3, W_ih, b_ih, W_hh, b_hh,
        Wr1, br1, Wr2, br2, Wr3, br3, aP, cnt, outp);
}